// Round 4
// baseline (584.984 us; speedup 1.0000x reference)
//
#include <hip/hip_runtime.h>
#include <math.h>

#define NEG_SLOPE 0.2f

typedef __attribute__((ext_vector_type(8))) short short8;
typedef __attribute__((ext_vector_type(4))) float f32x4;

__device__ __forceinline__ float leaky(float x) { return x > 0.f ? x : NEG_SLOPE * x; }
// monotonic float->uint encoding for atomicMax on floats
__device__ __forceinline__ unsigned enc(float f) {
    unsigned u = __float_as_uint(f);
    return (u & 0x80000000u) ? ~u : (u | 0x80000000u);
}
__device__ __forceinline__ float dec(unsigned e) {
    return (e & 0x80000000u) ? __uint_as_float(e ^ 0x80000000u) : __uint_as_float(~e);
}
// fp32 -> bf16 (RNE) as ushort bits
__device__ __forceinline__ unsigned bf16u(float f) {
    unsigned u = __float_as_uint(f);
    return (u + 0x7fffu + ((u >> 16) & 1u)) >> 16;
}
__device__ __forceinline__ float blo(unsigned u) { return __uint_as_float(u << 16); }
__device__ __forceinline__ float bhi(unsigned u) { return __uint_as_float(u & 0xffff0000u); }

// ---------------- merged prep: cvt x->bf16 | W0->W0T bf16 | fuse W1|Wres --------
__global__ __launch_bounds__(256) void prep_kernel(const float* __restrict__ x,
                                                   unsigned short* __restrict__ xb,
                                                   const float* __restrict__ W0,
                                                   unsigned short* __restrict__ W0T,
                                                   const float* __restrict__ W1,
                                                   const float* __restrict__ Wres,
                                                   float* __restrict__ Bcat, int nbx) {
    int b = blockIdx.x, tid = threadIdx.x;
    if (b < nbx) {                       // x -> bf16, 4 floats/thread
        int i = b * 256 + tid;
        float4 v = ((const float4*)x)[i];
        uint2 o;
        o.x = bf16u(v.x) | (bf16u(v.y) << 16);
        o.y = bf16u(v.z) | (bf16u(v.w) << 16);
        ((uint2*)xb)[i] = o;
    } else if (b < nbx + 256) {          // W0 [k][n] -> W0T [n][k] bf16
        int n = b - nbx, k = tid;
        W0T[n * 256 + k] = (unsigned short)bf16u(W0[k * 256 + n]);
    } else {                             // fuse W1|Wres -> Bcat [256][64]
        int i = (b - nbx - 256) * 256 + tid;
        int r = i >> 6, c = i & 63;
        Bcat[i] = (c < 32) ? W1[r * 32 + c] : Wres[r * 32 + (c - 32)];
    }
}

// ---------------- bf16 MFMA GEMM: writes DIM-SLICED feat: featS[c][row][32] ------
// A bf16 [M,K] row-major; Bt bf16 [Nc,K] row-major. grid (ceil(M/64), Nc/64).
__global__ __launch_bounds__(256) void gemm_bf16(const unsigned short* __restrict__ A,
                                                 const unsigned short* __restrict__ Bt,
                                                 unsigned short* __restrict__ featS,
                                                 int M, int Nc, int K) {
    __shared__ unsigned short As[64 * 40];
    __shared__ unsigned short Bs[64 * 40];
    int tid = threadIdx.x, lane = tid & 63, wv = tid >> 6;
    int m0 = blockIdx.x * 64, n0 = blockIdx.y * 64;
    int wm = (wv >> 1) * 32, wn = (wv & 1) * 32;
    f32x4 acc[2][2] = {};
    int srow = tid >> 2, scol = (tid & 3) * 8;
    bool avalid = (m0 + srow) < M;
    const unsigned short* Ap = A + (size_t)min(m0 + srow, M - 1) * K + scol;
    const unsigned short* Bp = Bt + (size_t)(n0 + srow) * K + scol;
    size_t N32 = (size_t)M * 32;

    for (int k0 = 0; k0 < K; k0 += 32) {
        float4 av = avalid ? *(const float4*)(Ap + k0) : make_float4(0.f, 0.f, 0.f, 0.f);
        float4 bv = *(const float4*)(Bp + k0);
        *(float4*)&As[srow * 40 + scol] = av;
        *(float4*)&Bs[srow * 40 + scol] = bv;
        __syncthreads();
        short8 af[2], bf[2];
#pragma unroll
        for (int i = 0; i < 2; ++i) {
            af[i] = *(const short8*)&As[(wm + i * 16 + (lane & 15)) * 40 + (lane >> 4) * 8];
            bf[i] = *(const short8*)&Bs[(wn + i * 16 + (lane & 15)) * 40 + (lane >> 4) * 8];
        }
#pragma unroll
        for (int i = 0; i < 2; ++i)
#pragma unroll
            for (int j = 0; j < 2; ++j)
                acc[i][j] = __builtin_amdgcn_mfma_f32_16x16x32_bf16(af[i], bf[j], acc[i][j], 0, 0, 0);
        __syncthreads();
    }
#pragma unroll
    for (int i = 0; i < 2; ++i) {
        int row0 = m0 + wm + i * 16 + (lane >> 4) * 4;
#pragma unroll
        for (int j = 0; j < 2; ++j) {
            int col = n0 + wn + j * 16 + (lane & 15);
            int ch = col >> 5, cc = col & 31;
            unsigned short* dst = featS + (size_t)ch * N32 + cc;
#pragma unroll
            for (int r = 0; r < 4; ++r) {
                int row = row0 + r;
                if (row < M) dst[(size_t)row * 32] = (unsigned short)bf16u(acc[i][j][r]);
            }
        }
    }
}

// ---------------- fp32 GEMM (layer 1, keeps residual path precise) ---------------
__global__ __launch_bounds__(256) void gemm_tile(const float* __restrict__ A,
                                                 const float* __restrict__ B,
                                                 float* __restrict__ C,
                                                 int M, int Nc, int K) {
    __shared__ float As[32][64];
    __shared__ float Bs[32][64];
    const int tid = threadIdx.x;
    const int m0 = blockIdx.x * 64;
    const int n0 = blockIdx.y * 64;
    const int tx = tid & 15, ty = tid >> 4;
    float acc[4][4] = {};
    for (int k0 = 0; k0 < K; k0 += 32) {
        {
            int r = tid >> 3, c4 = tid & 7;
#pragma unroll
            for (int l = 0; l < 2; ++l) {
                int row = r + l * 32;
                float4 v = make_float4(0.f, 0.f, 0.f, 0.f);
                if (m0 + row < M) v = *(const float4*)&A[(size_t)(m0 + row) * K + k0 + c4 * 4];
                As[c4 * 4 + 0][row] = v.x;
                As[c4 * 4 + 1][row] = v.y;
                As[c4 * 4 + 2][row] = v.z;
                As[c4 * 4 + 3][row] = v.w;
            }
        }
        {
            int kr = tid >> 4, c4 = tid & 15;
#pragma unroll
            for (int l = 0; l < 2; ++l) {
                int row = kr + l * 16;
                float4 v = *(const float4*)&B[(size_t)(k0 + row) * Nc + n0 + c4 * 4];
                *(float4*)&Bs[row][c4 * 4] = v;
            }
        }
        __syncthreads();
#pragma unroll
        for (int k = 0; k < 32; ++k) {
            float a0 = As[k][ty * 4 + 0], a1 = As[k][ty * 4 + 1];
            float a2 = As[k][ty * 4 + 2], a3 = As[k][ty * 4 + 3];
            float4 b = *(const float4*)&Bs[k][tx * 4];
            acc[0][0] += a0 * b.x; acc[0][1] += a0 * b.y; acc[0][2] += a0 * b.z; acc[0][3] += a0 * b.w;
            acc[1][0] += a1 * b.x; acc[1][1] += a1 * b.y; acc[1][2] += a1 * b.z; acc[1][3] += a1 * b.w;
            acc[2][0] += a2 * b.x; acc[2][1] += a2 * b.y; acc[2][2] += a2 * b.z; acc[2][3] += a2 * b.w;
            acc[3][0] += a3 * b.x; acc[3][1] += a3 * b.y; acc[3][2] += a3 * b.z; acc[3][3] += a3 * b.w;
        }
        __syncthreads();
    }
#pragma unroll
    for (int i = 0; i < 4; ++i) {
        int row = m0 + ty * 4 + i;
        if (row < M) {
            float4 v = make_float4(acc[i][0], acc[i][1], acc[i][2], acc[i][3]);
            *(float4*)&C[(size_t)row * Nc + n0 + tx * 4] = v;
        }
    }
}

// ------------- layer0 el/er from SLICED bf16 feat; 1 atomic per writer ----------
__global__ __launch_bounds__(128) void elr0_kernel(const unsigned short* __restrict__ featS,
                                                   const float* __restrict__ al,
                                                   const float* __restrict__ ar,
                                                   float* __restrict__ el, float* __restrict__ er,
                                                   unsigned* __restrict__ gmax, int N) {
    int tid = threadIdx.x;           // dims 2*tid, 2*tid+1
    int h = tid >> 5;
    const unsigned short* F = featS + (size_t)(tid >> 4) * ((size_t)N * 32);
    int cc = (tid & 15) * 2;
    float a0 = al[tid * 2], a1 = al[tid * 2 + 1];
    float r0 = ar[tid * 2], r1 = ar[tid * 2 + 1];
    float mpe = -1e30f, mpr = -1e30f;
    bool writer = (tid & 31) == 0;
    for (int n = blockIdx.x; n < N; n += gridDim.x) {
        unsigned u = *(const unsigned*)&F[(size_t)n * 32 + cc];
        float f0 = blo(u), f1 = bhi(u);
        float pe = f0 * a0 + f1 * a1;
        float pr = f0 * r0 + f1 * r1;
#pragma unroll
        for (int o = 16; o > 0; o >>= 1) {
            pe += __shfl_xor(pe, o);
            pr += __shfl_xor(pr, o);
        }
        if (writer) {
            el[n * 4 + h] = pe;
            er[n * 4 + h] = pr;
            mpe = fmaxf(mpe, pe);
            mpr = fmaxf(mpr, pr);
        }
    }
    if (writer) {
        atomicMax(&gmax[h], enc(mpe));
        atomicMax(&gmax[4 + h], enc(mpr));
    }
}

// ------------- layer1 el/er: 2 nodes per wave ------------------------------------
__global__ __launch_bounds__(256) void elr1_kernel(const float* __restrict__ fcat,
                                                   const float* __restrict__ al,
                                                   const float* __restrict__ ar,
                                                   float* __restrict__ el, float* __restrict__ er,
                                                   unsigned* __restrict__ gmax, int N) {
    int tid = threadIdx.x;
    int lane = tid & 63, wv = tid >> 6;
    int gw = blockIdx.x * 4 + wv;
    int d = lane & 31, half = lane >> 5;
    int stride = gridDim.x * 8;
    float a = al[d], r = ar[d];
    float mpe = -1e30f, mpr = -1e30f;
    bool writer = (lane & 31) == 0;
    for (int n0 = gw * 2; n0 < N; n0 += stride) {
        int n = n0 + half;
        float v = (n < N) ? fcat[(size_t)n * 64 + d] : 0.f;
        float pe = v * a, pr = v * r;
#pragma unroll
        for (int o = 16; o > 0; o >>= 1) {
            pe += __shfl_xor(pe, o);
            pr += __shfl_xor(pr, o);
        }
        if (writer && n < N) {
            el[n] = pe;
            er[n] = pr;
            mpe = fmaxf(mpe, pe);
            mpr = fmaxf(mpr, pr);
        }
    }
    if (writer) {
        atomicMax(&gmax[8], enc(mpe));
        atomicMax(&gmax[9], enc(mpr));
    }
}

// ------------- CSR build ---------------------------------------------------------
__global__ void count_kernel(const int* __restrict__ dst, int* __restrict__ deg, int E) {
    int e = blockIdx.x * 256 + threadIdx.x;
    if (e < E) atomicAdd(&deg[dst[e]], 1);
}

__global__ __launch_bounds__(256) void scanA(const int* __restrict__ deg, int* __restrict__ bsum, int N) {
    int i = blockIdx.x * 256 + threadIdx.x;
    int v = (i < N) ? deg[i] : 0;
#pragma unroll
    for (int o = 32; o > 0; o >>= 1) v += __shfl_xor(v, o);
    __shared__ int s[4];
    if ((threadIdx.x & 63) == 0) s[threadIdx.x >> 6] = v;
    __syncthreads();
    if (threadIdx.x == 0) bsum[blockIdx.x] = s[0] + s[1] + s[2] + s[3];
}

__global__ __launch_bounds__(256) void scanB(const int* __restrict__ bsum, int* __restrict__ bpre, int nb) {
    __shared__ int s[256];
    int t = threadIdx.x;
    int v = (t < nb) ? bsum[t] : 0;
    s[t] = v;
    __syncthreads();
    for (int o = 1; o < 256; o <<= 1) {
        int x = (t >= o) ? s[t - o] : 0;
        __syncthreads();
        s[t] += x;
        __syncthreads();
    }
    if (t < nb) bpre[t] = s[t] - v;  // exclusive
}

__global__ __launch_bounds__(256) void scanC(const int* __restrict__ deg, const int* __restrict__ bpre,
                                             int* __restrict__ off, int N) {
    int b = blockIdx.x, t = threadIdx.x;
    int i = b * 256 + t;
    int v = (i < N) ? deg[i] : 0;
    __shared__ int s[256];
    s[t] = v;
    __syncthreads();
    for (int o = 1; o < 256; o <<= 1) {
        int x = (t >= o) ? s[t - o] : 0;
        __syncthreads();
        s[t] += x;
        __syncthreads();
    }
    int incl = s[t];
    int base = bpre[b];
    if (i < N) off[i] = base + incl - v;
    if (i == N - 1) off[N] = base + incl;
}

__global__ void scatter_kernel(const int* __restrict__ src, const int* __restrict__ dst,
                               const int* __restrict__ off, int* __restrict__ cursor,
                               int* __restrict__ csr_src, int E) {
    int e = blockIdx.x * 256 + threadIdx.x;
    if (e < E) {
        int d = dst[e];
        int pos = atomicAdd(&cursor[d], 1);
        csr_src[off[d] + pos] = src[e];
    }
}

// ------------- layer0 normalized alphas in CSR order: csr_w[slot*4+h] ------------
__global__ __launch_bounds__(256) void w0norm(const float* __restrict__ el,
                                              const float* __restrict__ er,
                                              const unsigned* __restrict__ gmax,
                                              const int* __restrict__ off,
                                              const int* __restrict__ csr_src,
                                              float* __restrict__ csr_w, int N) {
    int tid = threadIdx.x, lane = tid & 63, wv = tid >> 6;
    int h = lane & 3;
    float C = leaky(dec(gmax[h]) + dec(gmax[4 + h]));
    for (int n = blockIdx.x * 4 + wv; n < N; n += gridDim.x * 4) {
        int base = off[n], deg = off[n + 1] - base;
        float ern = er[n * 4 + h];
        float den = 0.f;
        for (int j0 = 0; j0 < deg; j0 += 16) {
            int j = j0 + (lane >> 2);
            bool v = j < deg;
            int idx = base + (v ? j : 0);
            int s = csr_src[idx];
            float e = 0.f;
            if (v) {
                e = __expf(leaky(el[s * 4 + h] + ern) - C);
                csr_w[idx * 4 + h] = e;
            }
            den += e;
        }
        den += __shfl_xor(den, 4);
        den += __shfl_xor(den, 8);
        den += __shfl_xor(den, 16);
        den += __shfl_xor(den, 32);
        float inv = 1.f / den;
        for (int j0 = 0; j0 < deg; j0 += 16) {
            int j = j0 + (lane >> 2);
            if (j < deg) csr_w[(base + j) * 4 + h] *= inv;
        }
    }
}

// ------------- layer1 normalized alphas: csr_a1[slot] ---------------------------
__global__ __launch_bounds__(256) void w1norm(const float* __restrict__ el,
                                              const float* __restrict__ er,
                                              const unsigned* __restrict__ gmax,
                                              const int* __restrict__ off,
                                              const int* __restrict__ csr_src,
                                              float* __restrict__ csr_a1, int N) {
    int tid = threadIdx.x, lane = tid & 63, wv = tid >> 6;
    float C = leaky(dec(gmax[8]) + dec(gmax[9]));
    for (int n = blockIdx.x * 4 + wv; n < N; n += gridDim.x * 4) {
        int base = off[n], deg = off[n + 1] - base;
        float ern = er[n];
        float den = 0.f;
        for (int j0 = 0; j0 < deg; j0 += 64) {
            int j = j0 + lane;
            bool v = j < deg;
            int idx = base + (v ? j : 0);
            int s = csr_src[idx];
            float e = 0.f;
            if (v) {
                e = __expf(leaky(el[s] + ern) - C);
                csr_a1[idx] = e;
            }
            den += e;
        }
#pragma unroll
        for (int o = 1; o <= 32; o <<= 1) den += __shfl_xor(den, o);
        float inv = 1.f / den;
        for (int j0 = 0; j0 < deg; j0 += 64) {
            int j = j0 + lane;
            if (j < deg) csr_a1[base + j] *= inv;
        }
    }
}

// ------------- layer0 aggregation: dim-sliced, XCD-local, 8 edges/pass ----------
// grid = G*8 blocks; chunk = blockIdx & 7 (round-robin -> one XCD per chunk).
__global__ __launch_bounds__(256) void agg0_kernel(const unsigned short* __restrict__ featS,
                                                   const float* __restrict__ csr_w,
                                                   const int* __restrict__ off,
                                                   const int* __restrict__ csr_src,
                                                   float* __restrict__ hout, int N) {
    int tid = threadIdx.x, lane = tid & 63, wv = tid >> 6;
    int c = blockIdx.x & 7;
    int g = blockIdx.x >> 3;
    int G = gridDim.x >> 3;
    int h = c >> 1;
    const unsigned short* F = featS + (size_t)c * ((size_t)N * 32);
    int sub = lane >> 3, ld = lane & 7;   // 8 edge-subgroups x 8 lanes (4 dims each)
    for (int n = g * 4 + wv; n < N; n += G * 4) {
        int base = off[n], deg = off[n + 1] - base;
        float a0 = 0.f, a1 = 0.f, a2 = 0.f, a3 = 0.f;
        for (int j0 = 0; j0 < deg; j0 += 8) {
            int j = j0 + sub;
            bool v = j < deg;
            int idx = base + (v ? j : 0);
            int s = csr_src[idx];
            float w = v ? csr_w[idx * 4 + h] : 0.f;
            uint2 u = *(const uint2*)&F[(size_t)s * 32 + ld * 4];
            a0 += w * blo(u.x);
            a1 += w * bhi(u.x);
            a2 += w * blo(u.y);
            a3 += w * bhi(u.y);
        }
#pragma unroll
        for (int o = 8; o <= 32; o <<= 1) {
            a0 += __shfl_xor(a0, o);
            a1 += __shfl_xor(a1, o);
            a2 += __shfl_xor(a2, o);
            a3 += __shfl_xor(a3, o);
        }
        if (sub == 0) {
            float4 o4;
            o4.x = a0 > 0.f ? a0 : expm1f(a0);
            o4.y = a1 > 0.f ? a1 : expm1f(a1);
            o4.z = a2 > 0.f ? a2 : expm1f(a2);
            o4.w = a3 > 0.f ? a3 : expm1f(a3);
            *(float4*)&hout[(size_t)n * 256 + c * 32 + ld * 4] = o4;
        }
    }
}

// ------------- layer1 aggregation + residual: 2 edges/pass ----------------------
__global__ __launch_bounds__(256) void agg1_kernel(const float* __restrict__ fcat,
                                                   const float* __restrict__ csr_a1,
                                                   const int* __restrict__ off,
                                                   const int* __restrict__ csr_src,
                                                   float* __restrict__ out, int N) {
    int tid = threadIdx.x, lane = tid & 63, wv = tid >> 6;
    int sub = lane >> 5, d = lane & 31;
    for (int n = blockIdx.x * 4 + wv; n < N; n += gridDim.x * 4) {
        int base = off[n], deg = off[n + 1] - base;
        float acc = 0.f;
        for (int j0 = 0; j0 < deg; j0 += 2) {
            int j = j0 + sub;
            bool v = j < deg;
            int idx = base + (v ? j : 0);
            int s = csr_src[idx];
            float w = v ? csr_a1[idx] : 0.f;
            acc += w * fcat[(size_t)s * 64 + d];
        }
        acc += __shfl_xor(acc, 32);
        if (sub == 0)
            out[(size_t)n * 32 + d] = acc + fcat[(size_t)n * 64 + 32 + d];
    }
}

extern "C" void kernel_launch(void* const* d_in, const int* in_sizes, int n_in,
                              void* d_out, int out_size, void* d_ws, size_t ws_size,
                              hipStream_t stream) {
    const float* x    = (const float*)d_in[0];
    const int*   src  = (const int*)d_in[1];
    const int*   dst  = (const int*)d_in[2];
    const float* W0   = (const float*)d_in[3];
    const float* al0  = (const float*)d_in[4];
    const float* ar0  = (const float*)d_in[5];
    const float* W1   = (const float*)d_in[6];
    const float* al1  = (const float*)d_in[7];
    const float* ar1  = (const float*)d_in[8];
    const float* Wres = (const float*)d_in[9];
    float* out = (float*)d_out;

    const int N = in_sizes[0] / 256;  // 50000
    const int E = in_sizes[1];        // 850000

    // workspace layout
    float* hbuf  = (float*)d_ws;                      // N*256 fp32
    float* fcat  = hbuf + (size_t)N * 256;            // N*64 fp32 (feat1 | hres)
    float* el0   = fcat + (size_t)N * 64;             // N*4
    float* er0   = el0 + (size_t)N * 4;               // N*4
    float* el1   = er0 + (size_t)N * 4;               // N
    float* er1   = el1 + N;                           // N
    float* Bcat  = er1 + N;                           // 256*64 fp32
    float* csr_w0 = Bcat + 256 * 64;                  // E*4 fp32 (normalized alphas L0)
    float* csr_a1 = csr_w0 + (size_t)E * 4;           // E fp32 (normalized alphas L1)
    unsigned short* featS = (unsigned short*)(csr_a1 + E);        // N*256 bf16 (sliced)
    unsigned short* xb    = featS + (size_t)N * 256;              // N*256 bf16
    unsigned short* W0T   = xb + (size_t)N * 256;                 // 256*256 bf16
    int*   deg    = (int*)(W0T + 256 * 256);          // N
    int*   cursor = deg + N;                          // N
    unsigned* gmax = (unsigned*)(cursor + N);         // 16
    int*   offs  = (int*)(gmax + 16);                 // N+1
    int*   bsum  = offs + N + 1;                      // 256
    int*   bpre  = bsum + 256;                        // 256
    int*   csr_src = bpre + 256;                      // E

    const int nb = (N + 255) / 256;
    const int eb = (E + 255) / 256;
    const int mb = (N + 63) / 64;
    const int nbx = N * 256 / 4 / 256;  // 12500

    // zero: deg, cursor, gmax (contiguous)
    hipMemsetAsync(deg, 0, (size_t)(2 * N + 16) * sizeof(int), stream);

    // merged prep
    prep_kernel<<<nbx + 256 + 64, 256, 0, stream>>>(x, xb, W0, W0T, W1, Wres, Bcat, nbx);

    // CSR build
    count_kernel<<<eb, 256, 0, stream>>>(dst, deg, E);
    scanA<<<nb, 256, 0, stream>>>(deg, bsum, N);
    scanB<<<1, 256, 0, stream>>>(bsum, bpre, nb);
    scanC<<<nb, 256, 0, stream>>>(deg, bpre, offs, N);
    scatter_kernel<<<eb, 256, 0, stream>>>(src, dst, offs, cursor, csr_src, E);

    // layer 0
    gemm_bf16<<<dim3(mb, 4), 256, 0, stream>>>(xb, W0T, featS, N, 256, 256);
    elr0_kernel<<<1024, 128, 0, stream>>>(featS, al0, ar0, el0, er0, gmax, N);
    w0norm<<<512, 256, 0, stream>>>(el0, er0, gmax, offs, csr_src, csr_w0, N);
    agg0_kernel<<<2048 * 8, 256, 0, stream>>>(featS, csr_w0, offs, csr_src, hbuf, N);

    // layer 1 (fp32 protects residual-path precision)
    gemm_tile<<<dim3(mb, 1), 256, 0, stream>>>(hbuf, Bcat, fcat, N, 64, 256);
    elr1_kernel<<<256, 256, 0, stream>>>(fcat, al1, ar1, el1, er1, gmax, N);
    w1norm<<<512, 256, 0, stream>>>(el1, er1, gmax, offs, csr_src, csr_a1, N);
    agg1_kernel<<<1024, 256, 0, stream>>>(fcat, csr_a1, offs, csr_src, out, N);
}

// Round 5
// 482.480 us; speedup vs baseline: 1.2125x; 1.2125x over previous
//
#include <hip/hip_runtime.h>
#include <math.h>

#define NEG_SLOPE 0.2f

typedef __attribute__((ext_vector_type(8))) short short8;
typedef __attribute__((ext_vector_type(4))) float f32x4;

__device__ __forceinline__ float leaky(float x) { return x > 0.f ? x : NEG_SLOPE * x; }
__device__ __forceinline__ unsigned enc(float f) {
    unsigned u = __float_as_uint(f);
    return (u & 0x80000000u) ? ~u : (u | 0x80000000u);
}
__device__ __forceinline__ float dec(unsigned e) {
    return (e & 0x80000000u) ? __uint_as_float(e ^ 0x80000000u) : __uint_as_float(~e);
}
__device__ __forceinline__ unsigned bf16u(float f) {
    unsigned u = __float_as_uint(f);
    return (u + 0x7fffu + ((u >> 16) & 1u)) >> 16;
}
__device__ __forceinline__ float blo(unsigned u) { return __uint_as_float(u << 16); }
__device__ __forceinline__ float bhi(unsigned u) { return __uint_as_float(u & 0xffff0000u); }

// ---------------- merged prep: x->bf16 | W0->W0T bf16 | [W1|Wres]^T -> Bt1 bf16 --
__global__ __launch_bounds__(256) void prep_kernel(const float* __restrict__ x,
                                                   unsigned short* __restrict__ xb,
                                                   const float* __restrict__ W0,
                                                   unsigned short* __restrict__ W0T,
                                                   const float* __restrict__ W1,
                                                   const float* __restrict__ Wres,
                                                   unsigned short* __restrict__ Bt1, int nbx) {
    int b = blockIdx.x, tid = threadIdx.x;
    if (b < nbx) {                       // x -> bf16, 4 floats/thread
        int i = b * 256 + tid;
        float4 v = ((const float4*)x)[i];
        uint2 o;
        o.x = bf16u(v.x) | (bf16u(v.y) << 16);
        o.y = bf16u(v.z) | (bf16u(v.w) << 16);
        ((uint2*)xb)[i] = o;
    } else if (b < nbx + 256) {          // W0 [k][n] -> W0T [n][k] bf16
        int n = b - nbx, k = tid;
        W0T[n * 256 + k] = (unsigned short)bf16u(W0[k * 256 + n]);
    } else {                             // Bt1[n][k] = (n<32 ? W1 : Wres)[k][n']
        int n = b - nbx - 256, k = tid;
        float v = (n < 32) ? W1[k * 32 + n] : Wres[k * 32 + (n - 32)];
        Bt1[n * 256 + k] = (unsigned short)bf16u(v);
    }
}

// ---------------- layer0 GEMM (bf16 MFMA) + sliced featS write + fused elr0 ------
// grid (ceil(M/64), 4); blockIdx.y == head. featS[c][row][32], c = 2*y + half.
__global__ __launch_bounds__(256) void gemm0_fused(const unsigned short* __restrict__ A,
                                                   const unsigned short* __restrict__ Bt,
                                                   unsigned short* __restrict__ featS,
                                                   float* __restrict__ el0, float* __restrict__ er0,
                                                   const float* __restrict__ al,
                                                   const float* __restrict__ ar,
                                                   unsigned* __restrict__ gmax, int M) {
    __shared__ unsigned short As[64 * 40];
    __shared__ unsigned short Bs[64 * 40];
    __shared__ __align__(16) unsigned short tile[64 * 72];
    __shared__ float sEl[64], sEr[64];
    const int K = 256;
    int tid = threadIdx.x, lane = tid & 63, wv = tid >> 6;
    int m0 = blockIdx.x * 64, y = blockIdx.y, n0 = y * 64;
    int wm = (wv >> 1) * 32, wn = (wv & 1) * 32;
    f32x4 acc[2][2] = {};
    int srow = tid >> 2, scol = (tid & 3) * 8;
    bool avalid = (m0 + srow) < M;
    const unsigned short* Ap = A + (size_t)min(m0 + srow, M - 1) * K + scol;
    const unsigned short* Bp = Bt + (size_t)(n0 + srow) * K + scol;

    for (int k0 = 0; k0 < K; k0 += 32) {
        float4 av = avalid ? *(const float4*)(Ap + k0) : make_float4(0.f, 0.f, 0.f, 0.f);
        float4 bv = *(const float4*)(Bp + k0);
        *(float4*)&As[srow * 40 + scol] = av;
        *(float4*)&Bs[srow * 40 + scol] = bv;
        __syncthreads();
        short8 af[2], bf[2];
#pragma unroll
        for (int i = 0; i < 2; ++i) {
            af[i] = *(const short8*)&As[(wm + i * 16 + (lane & 15)) * 40 + (lane >> 4) * 8];
            bf[i] = *(const short8*)&Bs[(wn + i * 16 + (lane & 15)) * 40 + (lane >> 4) * 8];
        }
#pragma unroll
        for (int i = 0; i < 2; ++i)
#pragma unroll
            for (int j = 0; j < 2; ++j)
                acc[i][j] = __builtin_amdgcn_mfma_f32_16x16x32_bf16(af[i], bf[j], acc[i][j], 0, 0, 0);
        __syncthreads();
    }
    // acc -> LDS tile (bf16)
#pragma unroll
    for (int i = 0; i < 2; ++i)
#pragma unroll
        for (int j = 0; j < 2; ++j)
#pragma unroll
            for (int r = 0; r < 4; ++r)
                tile[(wm + i * 16 + (lane >> 4) * 4 + r) * 72 + wn + j * 16 + (lane & 15)] =
                    (unsigned short)bf16u(acc[i][j][r]);
    __syncthreads();
    // coalesced sliced featS write: 2 x uint4 per thread
    size_t N32 = (size_t)M * 32;
#pragma unroll
    for (int u = tid; u < 512; u += 256) {
        int ch = u >> 8, node = (u >> 2) & 63, part = u & 3;
        int row = m0 + node;
        if (row < M) {
            uint4 v = *(const uint4*)&tile[node * 72 + ch * 32 + part * 8];
            *(uint4*)&featS[(size_t)(2 * y + ch) * N32 + (size_t)row * 32 + part * 8] = v;
        }
    }
    // fused elr0: block has head y's full 64 dims
    {
        int row = tid >> 2, qr = tid & 3;
        float pe = 0.f, pr = 0.f;
        for (int k = 0; k < 16; ++k) {
            int c = qr * 16 + k;
            float f = __uint_as_float((unsigned)tile[row * 72 + c] << 16);
            pe += f * al[n0 + c];
            pr += f * ar[n0 + c];
        }
        pe += __shfl_xor(pe, 1); pe += __shfl_xor(pe, 2);
        pr += __shfl_xor(pr, 1); pr += __shfl_xor(pr, 2);
        if (qr == 0) {
            bool vv = (m0 + row) < M;
            if (vv) {
                el0[(m0 + row) * 4 + y] = pe;
                er0[(m0 + row) * 4 + y] = pr;
            }
            sEl[row] = vv ? pe : -1e30f;
            sEr[row] = vv ? pr : -1e30f;
        }
    }
    __syncthreads();
    if (tid < 64) {
        float m = sEl[tid];
#pragma unroll
        for (int o = 1; o <= 32; o <<= 1) m = fmaxf(m, __shfl_xor(m, o));
        if (tid == 0) atomicMax(&gmax[y], enc(m));
    } else if (tid < 128) {
        float m = sEr[tid - 64];
#pragma unroll
        for (int o = 1; o <= 32; o <<= 1) m = fmaxf(m, __shfl_xor(m, o));
        if (tid == 64) atomicMax(&gmax[4 + y], enc(m));
    }
}

// ---------------- layer1 GEMM (bf16 MFMA, fp32 out) + fused elr1 -----------------
// grid (ceil(M/64), 1). A = hb bf16 [M,256]; Bt1 bf16 [64,256]; fcat fp32 [M,64].
__global__ __launch_bounds__(256) void gemm1_fused(const unsigned short* __restrict__ A,
                                                   const unsigned short* __restrict__ Bt,
                                                   float* __restrict__ fcat,
                                                   float* __restrict__ el1, float* __restrict__ er1,
                                                   const float* __restrict__ al,
                                                   const float* __restrict__ ar,
                                                   unsigned* __restrict__ gmax, int M) {
    __shared__ unsigned short As[64 * 40];
    __shared__ unsigned short Bs[64 * 40];
    __shared__ __align__(16) float tileF[64 * 68];
    __shared__ float sEl[64], sEr[64];
    const int K = 256;
    int tid = threadIdx.x, lane = tid & 63, wv = tid >> 6;
    int m0 = blockIdx.x * 64;
    int wm = (wv >> 1) * 32, wn = (wv & 1) * 32;
    f32x4 acc[2][2] = {};
    int srow = tid >> 2, scol = (tid & 3) * 8;
    bool avalid = (m0 + srow) < M;
    const unsigned short* Ap = A + (size_t)min(m0 + srow, M - 1) * K + scol;
    const unsigned short* Bp = Bt + (size_t)srow * K + scol;

    for (int k0 = 0; k0 < K; k0 += 32) {
        float4 av = avalid ? *(const float4*)(Ap + k0) : make_float4(0.f, 0.f, 0.f, 0.f);
        float4 bv = *(const float4*)(Bp + k0);
        *(float4*)&As[srow * 40 + scol] = av;
        *(float4*)&Bs[srow * 40 + scol] = bv;
        __syncthreads();
        short8 af[2], bf[2];
#pragma unroll
        for (int i = 0; i < 2; ++i) {
            af[i] = *(const short8*)&As[(wm + i * 16 + (lane & 15)) * 40 + (lane >> 4) * 8];
            bf[i] = *(const short8*)&Bs[(wn + i * 16 + (lane & 15)) * 40 + (lane >> 4) * 8];
        }
#pragma unroll
        for (int i = 0; i < 2; ++i)
#pragma unroll
            for (int j = 0; j < 2; ++j)
                acc[i][j] = __builtin_amdgcn_mfma_f32_16x16x32_bf16(af[i], bf[j], acc[i][j], 0, 0, 0);
        __syncthreads();
    }
    // acc -> LDS tile (fp32)
#pragma unroll
    for (int i = 0; i < 2; ++i)
#pragma unroll
        for (int j = 0; j < 2; ++j)
#pragma unroll
            for (int r = 0; r < 4; ++r)
                tileF[(wm + i * 16 + (lane >> 4) * 4 + r) * 68 + wn + j * 16 + (lane & 15)] =
                    acc[i][j][r];
    __syncthreads();
    // coalesced fcat write: 4 x uint4 per thread
#pragma unroll
    for (int u = tid; u < 1024; u += 256) {
        int node = u >> 4, part = u & 15;
        int row = m0 + node;
        if (row < M)
            *(uint4*)&fcat[(size_t)row * 64 + part * 4] = *(const uint4*)&tileF[node * 68 + part * 4];
    }
    // fused elr1 (cols 0..31 hold h@W1)
    {
        int row = tid >> 2, qr = tid & 3;
        float pe = 0.f, pr = 0.f;
        for (int k = 0; k < 8; ++k) {
            int c = qr * 8 + k;
            float f = tileF[row * 68 + c];
            pe += f * al[c];
            pr += f * ar[c];
        }
        pe += __shfl_xor(pe, 1); pe += __shfl_xor(pe, 2);
        pr += __shfl_xor(pr, 1); pr += __shfl_xor(pr, 2);
        if (qr == 0) {
            bool vv = (m0 + row) < M;
            if (vv) {
                el1[m0 + row] = pe;
                er1[m0 + row] = pr;
            }
            sEl[row] = vv ? pe : -1e30f;
            sEr[row] = vv ? pr : -1e30f;
        }
    }
    __syncthreads();
    if (tid < 64) {
        float m = sEl[tid];
#pragma unroll
        for (int o = 1; o <= 32; o <<= 1) m = fmaxf(m, __shfl_xor(m, o));
        if (tid == 0) atomicMax(&gmax[8], enc(m));
    } else if (tid < 128) {
        float m = sEr[tid - 64];
#pragma unroll
        for (int o = 1; o <= 32; o <<= 1) m = fmaxf(m, __shfl_xor(m, o));
        if (tid == 64) atomicMax(&gmax[9], enc(m));
    }
}

// ------------- CSR build ---------------------------------------------------------
__global__ void count_kernel(const int* __restrict__ dst, int* __restrict__ deg, int E) {
    int e = blockIdx.x * 256 + threadIdx.x;
    if (e < E) atomicAdd(&deg[dst[e]], 1);
}

__global__ __launch_bounds__(256) void scanA(const int* __restrict__ deg, int* __restrict__ bsum, int N) {
    int i = blockIdx.x * 256 + threadIdx.x;
    int v = (i < N) ? deg[i] : 0;
#pragma unroll
    for (int o = 32; o > 0; o >>= 1) v += __shfl_xor(v, o);
    __shared__ int s[4];
    if ((threadIdx.x & 63) == 0) s[threadIdx.x >> 6] = v;
    __syncthreads();
    if (threadIdx.x == 0) bsum[blockIdx.x] = s[0] + s[1] + s[2] + s[3];
}

__global__ __launch_bounds__(256) void scanB(const int* __restrict__ bsum, int* __restrict__ bpre, int nb) {
    __shared__ int s[256];
    int t = threadIdx.x;
    int v = (t < nb) ? bsum[t] : 0;
    s[t] = v;
    __syncthreads();
    for (int o = 1; o < 256; o <<= 1) {
        int x = (t >= o) ? s[t - o] : 0;
        __syncthreads();
        s[t] += x;
        __syncthreads();
    }
    if (t < nb) bpre[t] = s[t] - v;  // exclusive
}

__global__ __launch_bounds__(256) void scanC(const int* __restrict__ deg, const int* __restrict__ bpre,
                                             int* __restrict__ off, int N) {
    int b = blockIdx.x, t = threadIdx.x;
    int i = b * 256 + t;
    int v = (i < N) ? deg[i] : 0;
    __shared__ int s[256];
    s[t] = v;
    __syncthreads();
    for (int o = 1; o < 256; o <<= 1) {
        int x = (t >= o) ? s[t - o] : 0;
        __syncthreads();
        s[t] += x;
        __syncthreads();
    }
    int incl = s[t];
    int base = bpre[b];
    if (i < N) off[i] = base + incl - v;
    if (i == N - 1) off[N] = base + incl;
}

__global__ void scatter_kernel(const int* __restrict__ src, const int* __restrict__ dst,
                               const int* __restrict__ off, int* __restrict__ cursor,
                               int* __restrict__ csr_src, int E) {
    int e = blockIdx.x * 256 + threadIdx.x;
    if (e < E) {
        int d = dst[e];
        int pos = atomicAdd(&cursor[d], 1);
        csr_src[off[d] + pos] = src[e];
    }
}

// ------------- layer0 packed normalized weights, planar per head -----------------
// pk0[h*E + slot] = (src_byte_offset_in_featS_chunk, alpha)
__global__ __launch_bounds__(256) void w0norm(const float* __restrict__ el,
                                              const float* __restrict__ er,
                                              const unsigned* __restrict__ gmax,
                                              const int* __restrict__ off,
                                              const int* __restrict__ csr_src,
                                              uint2* __restrict__ pk0, int N, int E) {
    int tid = threadIdx.x, lane = tid & 63, wv = tid >> 6;
    int h = lane >> 4, j = lane & 15;
    float C = leaky(dec(gmax[h]) + dec(gmax[4 + h]));
    uint2* PH = pk0 + (size_t)h * E;
    for (int n = blockIdx.x * 4 + wv; n < N; n += gridDim.x * 4) {
        int base = off[n], deg = off[n + 1] - base;
        float ern = er[n * 4 + h];
        float den = 0.f;
        for (int j0 = 0; j0 < deg; j0 += 16) {
            int jj = j0 + j;
            bool v = jj < deg;
            int idx = base + (v ? jj : 0);
            int s = csr_src[idx];
            float e = 0.f;
            if (v) {
                e = __expf(leaky(el[s * 4 + h] + ern) - C);
                PH[idx] = make_uint2((unsigned)(s * 64), __float_as_uint(e));
            }
            den += e;
        }
        den += __shfl_xor(den, 1);
        den += __shfl_xor(den, 2);
        den += __shfl_xor(den, 4);
        den += __shfl_xor(den, 8);
        float inv = 1.f / den;
        for (int j0 = 0; j0 < deg; j0 += 16) {
            int jj = j0 + j;
            if (jj < deg) {
                unsigned* py = &PH[base + jj].y;
                *py = __float_as_uint(__uint_as_float(*py) * inv);
            }
        }
    }
}

// ------------- layer1 packed normalized weights ----------------------------------
// pk1[slot] = (src_byte_offset_in_fcat, alpha)
__global__ __launch_bounds__(256) void w1norm(const float* __restrict__ el,
                                              const float* __restrict__ er,
                                              const unsigned* __restrict__ gmax,
                                              const int* __restrict__ off,
                                              const int* __restrict__ csr_src,
                                              uint2* __restrict__ pk1, int N) {
    int tid = threadIdx.x, lane = tid & 63, wv = tid >> 6;
    float C = leaky(dec(gmax[8]) + dec(gmax[9]));
    for (int n = blockIdx.x * 4 + wv; n < N; n += gridDim.x * 4) {
        int base = off[n], deg = off[n + 1] - base;
        float ern = er[n];
        float den = 0.f;
        for (int j0 = 0; j0 < deg; j0 += 64) {
            int jj = j0 + lane;
            bool v = jj < deg;
            int idx = base + (v ? jj : 0);
            int s = csr_src[idx];
            float e = 0.f;
            if (v) {
                e = __expf(leaky(el[s] + ern) - C);
                pk1[idx] = make_uint2((unsigned)(s * 256), __float_as_uint(e));
            }
            den += e;
        }
#pragma unroll
        for (int o = 1; o <= 32; o <<= 1) den += __shfl_xor(den, o);
        float inv = 1.f / den;
        for (int j0 = 0; j0 < deg; j0 += 64) {
            int jj = j0 + lane;
            if (jj < deg) {
                unsigned* py = &pk1[base + jj].y;
                *py = __float_as_uint(__uint_as_float(*py) * inv);
            }
        }
    }
}

// ------------- layer0 aggregation: dim-sliced XCD-local, packed stream, ELU ------
// grid = G*8; chunk = blockIdx & 7. Writes hb (bf16 [N][256]).
__global__ __launch_bounds__(256) void agg0_kernel(const unsigned short* __restrict__ featS,
                                                   const uint2* __restrict__ pk0,
                                                   const int* __restrict__ off,
                                                   unsigned short* __restrict__ hb, int N, int E) {
    int tid = threadIdx.x, lane = tid & 63, wv = tid >> 6;
    int c = blockIdx.x & 7;
    int g = blockIdx.x >> 3;
    int G = gridDim.x >> 3;
    int h = c >> 1;
    int sub = lane >> 3, ld = lane & 7;
    const char* Fb = (const char*)(featS + (size_t)c * ((size_t)N * 32)) + ld * 8;
    const uint2* PH = pk0 + (size_t)h * E;
    for (int n = g * 4 + wv; n < N; n += G * 4) {
        int base = off[n], deg = off[n + 1] - base;
        float a0 = 0.f, a1 = 0.f, a2 = 0.f, a3 = 0.f;
        for (int j0 = 0; j0 < deg; j0 += 8) {
            int jj = j0 + sub;
            bool v = jj < deg;
            uint2 p = PH[base + (v ? jj : 0)];
            float w = v ? __uint_as_float(p.y) : 0.f;
            uint2 u = *(const uint2*)(Fb + p.x);
            a0 += w * blo(u.x);
            a1 += w * bhi(u.x);
            a2 += w * blo(u.y);
            a3 += w * bhi(u.y);
        }
#pragma unroll
        for (int o = 8; o <= 32; o <<= 1) {
            a0 += __shfl_xor(a0, o);
            a1 += __shfl_xor(a1, o);
            a2 += __shfl_xor(a2, o);
            a3 += __shfl_xor(a3, o);
        }
        if (sub == 0) {
            a0 = a0 > 0.f ? a0 : expm1f(a0);
            a1 = a1 > 0.f ? a1 : expm1f(a1);
            a2 = a2 > 0.f ? a2 : expm1f(a2);
            a3 = a3 > 0.f ? a3 : expm1f(a3);
            uint2 o2;
            o2.x = bf16u(a0) | (bf16u(a1) << 16);
            o2.y = bf16u(a2) | (bf16u(a3) << 16);
            *(uint2*)&hb[(size_t)n * 256 + c * 32 + ld * 4] = o2;
        }
    }
}

// ------------- layer1 aggregation + residual -------------------------------------
__global__ __launch_bounds__(256) void agg1_kernel(const float* __restrict__ fcat,
                                                   const uint2* __restrict__ pk1,
                                                   const int* __restrict__ off,
                                                   float* __restrict__ out, int N) {
    int tid = threadIdx.x, lane = tid & 63, wv = tid >> 6;
    int sub = lane >> 5, d = lane & 31;
    const char* Fb = (const char*)fcat + d * 4;
    for (int n = blockIdx.x * 4 + wv; n < N; n += gridDim.x * 4) {
        int base = off[n], deg = off[n + 1] - base;
        float acc = 0.f;
        for (int j0 = 0; j0 < deg; j0 += 2) {
            int jj = j0 + sub;
            bool v = jj < deg;
            uint2 p = pk1[base + (v ? jj : 0)];
            float w = v ? __uint_as_float(p.y) : 0.f;
            acc += w * *(const float*)(Fb + p.x);
        }
        acc += __shfl_xor(acc, 32);
        if (sub == 0)
            out[(size_t)n * 32 + d] = acc + fcat[(size_t)n * 64 + 32 + d];
    }
}

extern "C" void kernel_launch(void* const* d_in, const int* in_sizes, int n_in,
                              void* d_out, int out_size, void* d_ws, size_t ws_size,
                              hipStream_t stream) {
    const float* x    = (const float*)d_in[0];
    const int*   src  = (const int*)d_in[1];
    const int*   dst  = (const int*)d_in[2];
    const float* W0   = (const float*)d_in[3];
    const float* al0  = (const float*)d_in[4];
    const float* ar0  = (const float*)d_in[5];
    const float* W1   = (const float*)d_in[6];
    const float* al1  = (const float*)d_in[7];
    const float* ar1  = (const float*)d_in[8];
    const float* Wres = (const float*)d_in[9];
    float* out = (float*)d_out;

    const int N = in_sizes[0] / 256;  // 50000
    const int E = in_sizes[1];        // 850000

    // workspace layout (16B-aligned chunks)
    unsigned short* hb    = (unsigned short*)d_ws;                // N*256 bf16 (layer0 out)
    unsigned short* featS = hb + (size_t)N * 256;                 // N*256 bf16, sliced [8][N][32]
    unsigned short* xb    = featS + (size_t)N * 256;              // N*256 bf16
    unsigned short* W0T   = xb + (size_t)N * 256;                 // 256*256 bf16
    unsigned short* Bt1   = W0T + 256 * 256;                      // 64*256 bf16
    float* fcat = (float*)(Bt1 + 64 * 256);                       // N*64 fp32
    float* el0  = fcat + (size_t)N * 64;                          // N*4
    float* er0  = el0 + (size_t)N * 4;                            // N*4
    float* el1  = er0 + (size_t)N * 4;                            // N
    float* er1  = el1 + N;                                        // N
    uint2* pk0  = (uint2*)(er1 + N);                              // E*4 (planar per head)
    uint2* pk1  = pk0 + (size_t)E * 4;                            // E
    int*   deg    = (int*)(pk1 + E);                              // N
    int*   cursor = deg + N;                                      // N
    unsigned* gmax = (unsigned*)(cursor + N);                     // 16
    int*   offs  = (int*)(gmax + 16);                             // N+1
    int*   bsum  = offs + N + 1;                                  // 256
    int*   bpre  = bsum + 256;                                    // 256
    int*   csr_src = bpre + 256;                                  // E

    const int nb = (N + 255) / 256;
    const int eb = (E + 255) / 256;
    const int mb = (N + 63) / 64;
    const int nbx = N * 256 / 4 / 256;  // 12500

    // zero: deg, cursor, gmax (contiguous)
    hipMemsetAsync(deg, 0, (size_t)(2 * N + 16) * sizeof(int), stream);

    // prep (conversions)
    prep_kernel<<<nbx + 256 + 64, 256, 0, stream>>>(x, xb, W0, W0T, W1, Wres, Bt1, nbx);

    // CSR build
    count_kernel<<<eb, 256, 0, stream>>>(dst, deg, E);
    scanA<<<nb, 256, 0, stream>>>(deg, bsum, N);
    scanB<<<1, 256, 0, stream>>>(bsum, bpre, nb);
    scanC<<<nb, 256, 0, stream>>>(deg, bpre, offs, N);
    scatter_kernel<<<eb, 256, 0, stream>>>(src, dst, offs, cursor, csr_src, E);

    // layer 0
    gemm0_fused<<<dim3(mb, 4), 256, 0, stream>>>(xb, W0T, featS, el0, er0, al0, ar0, gmax, N);
    w0norm<<<512, 256, 0, stream>>>(el0, er0, gmax, offs, csr_src, pk0, N, E);
    agg0_kernel<<<1024 * 8, 256, 0, stream>>>(featS, pk0, offs, hb, N, E);

    // layer 1
    gemm1_fused<<<dim3(mb, 1), 256, 0, stream>>>(hb, Bt1, fcat, el1, er1, al1, ar1, gmax, N);
    w1norm<<<512, 256, 0, stream>>>(el1, er1, gmax, offs, csr_src, pk1, N);
    agg1_kernel<<<2048, 256, 0, stream>>>(fcat, pk1, offs, out, N);
}

// Round 6
// 358.153 us; speedup vs baseline: 1.6333x; 1.3471x over previous
//
#include <hip/hip_runtime.h>
#include <math.h>

#define NEG_SLOPE 0.2f

typedef __attribute__((ext_vector_type(8))) short short8;
typedef __attribute__((ext_vector_type(4))) float f32x4;

__device__ __forceinline__ float leaky(float x) { return x > 0.f ? x : NEG_SLOPE * x; }
__device__ __forceinline__ unsigned enc(float f) {
    unsigned u = __float_as_uint(f);
    return (u & 0x80000000u) ? ~u : (u | 0x80000000u);
}
__device__ __forceinline__ float dec(unsigned e) {
    return (e & 0x80000000u) ? __uint_as_float(e ^ 0x80000000u) : __uint_as_float(~e);
}
__device__ __forceinline__ unsigned bf16u(float f) {
    unsigned u = __float_as_uint(f);
    return (u + 0x7fffu + ((u >> 16) & 1u)) >> 16;
}
__device__ __forceinline__ float blo(unsigned u) { return __uint_as_float(u << 16); }
__device__ __forceinline__ float bhi(unsigned u) { return __uint_as_float(u & 0xffff0000u); }

// ---- prep: W0 -> panel-major bf16 W0P[8][256][32] | [W1|Wres]^T -> Bt1 | count ---
__global__ __launch_bounds__(256) void prep_kernel(const float* __restrict__ W0,
                                                   unsigned short* __restrict__ W0P,
                                                   const float* __restrict__ W1,
                                                   const float* __restrict__ Wres,
                                                   unsigned short* __restrict__ Bt1,
                                                   const int* __restrict__ dst,
                                                   int* __restrict__ deg, int E) {
    int b = blockIdx.x, tid = threadIdx.x;
    if (b < 256) {                        // W0P[k>>5][n][k&31] = W0[k][n]
        int n = b, k = tid;
        W0P[(k >> 5) * 8192 + n * 32 + (k & 31)] = (unsigned short)bf16u(W0[k * 256 + n]);
    } else if (b < 320) {                 // Bt1[n][k]
        int n = b - 256, k = tid;
        float v = (n < 32) ? W1[k * 32 + n] : Wres[k * 32 + (n - 32)];
        Bt1[n * 256 + k] = (unsigned short)bf16u(v);
    } else {                              // degree count
        int e = (b - 320) * 256 + tid;
        if (e < E) atomicAdd(&deg[dst[e]], 1);
    }
}

// ---- layer0 GEMM, all 4 heads per block; fp32 A converted in staging; fused elr0 --
// grid (ceil(M/64)); LDS: As 5KB + Bs 20KB + tile 9.2KB + sEl/sEr 2KB.
__global__ __launch_bounds__(256) void gemm0_all(const float* __restrict__ x,
                                                 const unsigned short* __restrict__ W0P,
                                                 unsigned short* __restrict__ featS,
                                                 float* __restrict__ el0, float* __restrict__ er0,
                                                 const float* __restrict__ al,
                                                 const float* __restrict__ ar,
                                                 unsigned* __restrict__ gmax, int M) {
    __shared__ unsigned short As[64 * 40];
    __shared__ unsigned short Bs[256 * 40];
    __shared__ __align__(16) unsigned short tile[64 * 72];
    __shared__ float sEl[4][64], sEr[4][64];
    const int K = 256;
    int tid = threadIdx.x, lane = tid & 63, wv = tid >> 6;
    int m0 = blockIdx.x * 64;
    int wm = (wv >> 1) * 32, wn = (wv & 1) * 32;
    f32x4 acc[4][2][2] = {};
    int arow = tid >> 2, apart = tid & 3;
    bool avalid = (m0 + arow) < M;
    const float* Ap = x + (size_t)min(m0 + arow, M - 1) * K + apart * 8;

    for (int k0 = 0; k0 < K; k0 += 32) {
        // A: 8 fp32 -> 8 bf16 -> 16B LDS
        float4 a0 = avalid ? *(const float4*)(Ap + k0) : make_float4(0.f, 0.f, 0.f, 0.f);
        float4 a1 = avalid ? *(const float4*)(Ap + k0 + 4) : make_float4(0.f, 0.f, 0.f, 0.f);
        uint4 ap;
        ap.x = bf16u(a0.x) | (bf16u(a0.y) << 16);
        ap.y = bf16u(a0.z) | (bf16u(a0.w) << 16);
        ap.z = bf16u(a1.x) | (bf16u(a1.y) << 16);
        ap.w = bf16u(a1.z) | (bf16u(a1.w) << 16);
        *(uint4*)&As[arow * 40 + apart * 8] = ap;
        // B: coalesced 16KB panel (k-slab) -> Bs
        const unsigned short* slab = W0P + (k0 >> 5) * 8192;
#pragma unroll
        for (int p = 0; p < 4; ++p) {
            int q = p * 256 + tid;                  // uint4 index in slab
            uint4 bv = *(const uint4*)(slab + q * 8);
            *(uint4*)&Bs[(q >> 2) * 40 + (q & 3) * 8] = bv;
        }
        __syncthreads();
        short8 af[2];
#pragma unroll
        for (int i = 0; i < 2; ++i)
            af[i] = *(const short8*)&As[(wm + i * 16 + (lane & 15)) * 40 + (lane >> 4) * 8];
#pragma unroll
        for (int y = 0; y < 4; ++y) {
            short8 bf[2];
#pragma unroll
            for (int j = 0; j < 2; ++j)
                bf[j] = *(const short8*)&Bs[(y * 64 + wn + j * 16 + (lane & 15)) * 40 + (lane >> 4) * 8];
#pragma unroll
            for (int i = 0; i < 2; ++i)
#pragma unroll
                for (int j = 0; j < 2; ++j)
                    acc[y][i][j] = __builtin_amdgcn_mfma_f32_16x16x32_bf16(af[i], bf[j], acc[y][i][j], 0, 0, 0);
        }
        __syncthreads();
    }
    size_t N32 = (size_t)M * 32;
    for (int y = 0; y < 4; ++y) {
        // dump acc[y] -> tile (bf16)
#pragma unroll
        for (int i = 0; i < 2; ++i)
#pragma unroll
            for (int j = 0; j < 2; ++j)
#pragma unroll
                for (int r = 0; r < 4; ++r)
                    tile[(wm + i * 16 + (lane >> 4) * 4 + r) * 72 + wn + j * 16 + (lane & 15)] =
                        (unsigned short)bf16u(acc[y][i][j][r]);
        __syncthreads();
        // sliced featS write (chunks 2y, 2y+1)
#pragma unroll
        for (int u = tid; u < 512; u += 256) {
            int ch = u >> 8, node = (u >> 2) & 63, part = u & 3;
            int row = m0 + node;
            if (row < M) {
                uint4 v = *(const uint4*)&tile[node * 72 + ch * 32 + part * 8];
                *(uint4*)&featS[(size_t)(2 * y + ch) * N32 + (size_t)row * 32 + part * 8] = v;
            }
        }
        // fused elr0 head y
        {
            int row = tid >> 2, qr = tid & 3;
            float pe = 0.f, pr = 0.f;
            for (int k2 = 0; k2 < 16; ++k2) {
                int c = qr * 16 + k2;
                float f = __uint_as_float((unsigned)tile[row * 72 + c] << 16);
                pe += f * al[y * 64 + c];
                pr += f * ar[y * 64 + c];
            }
            pe += __shfl_xor(pe, 1); pe += __shfl_xor(pe, 2);
            pr += __shfl_xor(pr, 1); pr += __shfl_xor(pr, 2);
            if (qr == 0) {
                bool vv = (m0 + row) < M;
                if (vv) {
                    el0[(m0 + row) * 4 + y] = pe;
                    er0[(m0 + row) * 4 + y] = pr;
                }
                sEl[y][row] = vv ? pe : -1e30f;
                sEr[y][row] = vv ? pr : -1e30f;
            }
        }
        __syncthreads();
    }
    // per-head gmax: wave wv reduces head wv
    {
        float m1 = sEl[wv][lane];
        float m2 = sEr[wv][lane];
#pragma unroll
        for (int o = 1; o <= 32; o <<= 1) {
            m1 = fmaxf(m1, __shfl_xor(m1, o));
            m2 = fmaxf(m2, __shfl_xor(m2, o));
        }
        if (lane == 0) atomicMax(&gmax[wv], enc(m1));
        if (lane == 1) atomicMax(&gmax[4 + wv], enc(m2));
    }
}

// ---- layer1 GEMM (bf16 MFMA, fp32 out) + fused elr1 -----------------------------
__global__ __launch_bounds__(256) void gemm1_fused(const unsigned short* __restrict__ A,
                                                   const unsigned short* __restrict__ Bt,
                                                   float* __restrict__ fcat,
                                                   float* __restrict__ el1, float* __restrict__ er1,
                                                   const float* __restrict__ al,
                                                   const float* __restrict__ ar,
                                                   unsigned* __restrict__ gmax, int M) {
    __shared__ unsigned short As[64 * 40];
    __shared__ unsigned short Bs[64 * 40];
    __shared__ __align__(16) float tileF[64 * 68];
    __shared__ float sEl[64], sEr[64];
    const int K = 256;
    int tid = threadIdx.x, lane = tid & 63, wv = tid >> 6;
    int m0 = blockIdx.x * 64;
    int wm = (wv >> 1) * 32, wn = (wv & 1) * 32;
    f32x4 acc[2][2] = {};
    int srow = tid >> 2, scol = (tid & 3) * 8;
    bool avalid = (m0 + srow) < M;
    const unsigned short* Ap = A + (size_t)min(m0 + srow, M - 1) * K + scol;
    const unsigned short* Bp = Bt + (size_t)srow * K + scol;

    for (int k0 = 0; k0 < K; k0 += 32) {
        float4 av = avalid ? *(const float4*)(Ap + k0) : make_float4(0.f, 0.f, 0.f, 0.f);
        float4 bv = *(const float4*)(Bp + k0);
        *(float4*)&As[srow * 40 + scol] = av;
        *(float4*)&Bs[srow * 40 + scol] = bv;
        __syncthreads();
        short8 af[2], bf[2];
#pragma unroll
        for (int i = 0; i < 2; ++i) {
            af[i] = *(const short8*)&As[(wm + i * 16 + (lane & 15)) * 40 + (lane >> 4) * 8];
            bf[i] = *(const short8*)&Bs[(wn + i * 16 + (lane & 15)) * 40 + (lane >> 4) * 8];
        }
#pragma unroll
        for (int i = 0; i < 2; ++i)
#pragma unroll
            for (int j = 0; j < 2; ++j)
                acc[i][j] = __builtin_amdgcn_mfma_f32_16x16x32_bf16(af[i], bf[j], acc[i][j], 0, 0, 0);
        __syncthreads();
    }
#pragma unroll
    for (int i = 0; i < 2; ++i)
#pragma unroll
        for (int j = 0; j < 2; ++j)
#pragma unroll
            for (int r = 0; r < 4; ++r)
                tileF[(wm + i * 16 + (lane >> 4) * 4 + r) * 68 + wn + j * 16 + (lane & 15)] =
                    acc[i][j][r];
    __syncthreads();
#pragma unroll
    for (int u = tid; u < 1024; u += 256) {
        int node = u >> 4, part = u & 15;
        int row = m0 + node;
        if (row < M)
            *(uint4*)&fcat[(size_t)row * 64 + part * 4] = *(const uint4*)&tileF[node * 68 + part * 4];
    }
    {
        int row = tid >> 2, qr = tid & 3;
        float pe = 0.f, pr = 0.f;
        for (int k = 0; k < 8; ++k) {
            int c = qr * 8 + k;
            float f = tileF[row * 68 + c];
            pe += f * al[c];
            pr += f * ar[c];
        }
        pe += __shfl_xor(pe, 1); pe += __shfl_xor(pe, 2);
        pr += __shfl_xor(pr, 1); pr += __shfl_xor(pr, 2);
        if (qr == 0) {
            bool vv = (m0 + row) < M;
            if (vv) {
                el1[m0 + row] = pe;
                er1[m0 + row] = pr;
            }
            sEl[row] = vv ? pe : -1e30f;
            sEr[row] = vv ? pr : -1e30f;
        }
    }
    __syncthreads();
    if (tid < 64) {
        float m = sEl[tid];
#pragma unroll
        for (int o = 1; o <= 32; o <<= 1) m = fmaxf(m, __shfl_xor(m, o));
        if (tid == 0) atomicMax(&gmax[8], enc(m));
    } else if (tid < 128) {
        float m = sEr[tid - 64];
#pragma unroll
        for (int o = 1; o <= 32; o <<= 1) m = fmaxf(m, __shfl_xor(m, o));
        if (tid == 64) atomicMax(&gmax[9], enc(m));
    }
}

// ------------- CSR scans + scatter ------------------------------------------------
__global__ __launch_bounds__(256) void scanA(const int* __restrict__ deg, int* __restrict__ bsum, int N) {
    int i = blockIdx.x * 256 + threadIdx.x;
    int v = (i < N) ? deg[i] : 0;
#pragma unroll
    for (int o = 32; o > 0; o >>= 1) v += __shfl_xor(v, o);
    __shared__ int s[4];
    if ((threadIdx.x & 63) == 0) s[threadIdx.x >> 6] = v;
    __syncthreads();
    if (threadIdx.x == 0) bsum[blockIdx.x] = s[0] + s[1] + s[2] + s[3];
}

__global__ __launch_bounds__(256) void scanB(const int* __restrict__ bsum, int* __restrict__ bpre, int nb) {
    __shared__ int s[256];
    int t = threadIdx.x;
    int v = (t < nb) ? bsum[t] : 0;
    s[t] = v;
    __syncthreads();
    for (int o = 1; o < 256; o <<= 1) {
        int x = (t >= o) ? s[t - o] : 0;
        __syncthreads();
        s[t] += x;
        __syncthreads();
    }
    if (t < nb) bpre[t] = s[t] - v;
}

__global__ __launch_bounds__(256) void scanC(const int* __restrict__ deg, const int* __restrict__ bpre,
                                             int* __restrict__ off, int N) {
    int b = blockIdx.x, t = threadIdx.x;
    int i = b * 256 + t;
    int v = (i < N) ? deg[i] : 0;
    __shared__ int s[256];
    s[t] = v;
    __syncthreads();
    for (int o = 1; o < 256; o <<= 1) {
        int x = (t >= o) ? s[t - o] : 0;
        __syncthreads();
        s[t] += x;
        __syncthreads();
    }
    int incl = s[t];
    int base = bpre[b];
    if (i < N) off[i] = base + incl - v;
    if (i == N - 1) off[N] = base + incl;
}

__global__ void scatter_kernel(const int* __restrict__ src, const int* __restrict__ dst,
                               const int* __restrict__ off, int* __restrict__ cursor,
                               int* __restrict__ csr_src, int E) {
    int e = blockIdx.x * 256 + threadIdx.x;
    if (e < E) {
        int d = dst[e];
        int pos = atomicAdd(&cursor[d], 1);
        csr_src[off[d] + pos] = src[e];
    }
}

// ---- layer0 weights (UNNORMALIZED) + reciprocal denominator ---------------------
__global__ __launch_bounds__(256) void w0norm(const float* __restrict__ el,
                                              const float* __restrict__ er,
                                              const unsigned* __restrict__ gmax,
                                              const int* __restrict__ off,
                                              const int* __restrict__ csr_src,
                                              uint2* __restrict__ pk0,
                                              float* __restrict__ dinv0, int N, int E) {
    int tid = threadIdx.x, lane = tid & 63, wv = tid >> 6;
    int h = lane >> 4, j = lane & 15;
    float C = leaky(dec(gmax[h]) + dec(gmax[4 + h]));
    uint2* PH = pk0 + (size_t)h * E;
    for (int n = blockIdx.x * 4 + wv; n < N; n += gridDim.x * 4) {
        int base = off[n], deg = off[n + 1] - base;
        float ern = er[n * 4 + h];
        float den = 0.f;
        for (int j0 = 0; j0 < deg; j0 += 16) {
            int jj = j0 + j;
            bool v = jj < deg;
            int idx = base + (v ? jj : 0);
            int s = csr_src[idx];
            float e = 0.f;
            if (v) {
                e = __expf(leaky(el[s * 4 + h] + ern) - C);
                PH[idx] = make_uint2((unsigned)(s * 64), __float_as_uint(e));
            }
            den += e;
        }
        den += __shfl_xor(den, 1);
        den += __shfl_xor(den, 2);
        den += __shfl_xor(den, 4);
        den += __shfl_xor(den, 8);
        if (j == 0) dinv0[n * 4 + h] = 1.f / den;
    }
}

// ---- layer1 weights (UNNORMALIZED) + reciprocal denominator ---------------------
__global__ __launch_bounds__(256) void w1norm(const float* __restrict__ el,
                                              const float* __restrict__ er,
                                              const unsigned* __restrict__ gmax,
                                              const int* __restrict__ off,
                                              const int* __restrict__ csr_src,
                                              uint2* __restrict__ pk1,
                                              float* __restrict__ dinv1, int N) {
    int tid = threadIdx.x, lane = tid & 63, wv = tid >> 6;
    float C = leaky(dec(gmax[8]) + dec(gmax[9]));
    for (int n = blockIdx.x * 4 + wv; n < N; n += gridDim.x * 4) {
        int base = off[n], deg = off[n + 1] - base;
        float ern = er[n];
        float den = 0.f;
        for (int j0 = 0; j0 < deg; j0 += 64) {
            int jj = j0 + lane;
            bool v = jj < deg;
            int idx = base + (v ? jj : 0);
            int s = csr_src[idx];
            float e = 0.f;
            if (v) {
                e = __expf(leaky(el[s] + ern) - C);
                pk1[idx] = make_uint2((unsigned)(s * 256), __float_as_uint(e));
            }
            den += e;
        }
#pragma unroll
        for (int o = 1; o <= 32; o <<= 1) den += __shfl_xor(den, o);
        float inv = 1.f / den;
        if (lane == 0) dinv1[n] = inv;
    }
}

// ---- layer0 aggregation: 4-lane group per node-chunk, private accumulation -------
// grid = G*8; chunk c = blockIdx&7 (XCD round-robin); head h = c>>1.
__global__ __launch_bounds__(256) void agg0_kernel(const unsigned short* __restrict__ featS,
                                                   const uint2* __restrict__ pk0,
                                                   const float* __restrict__ dinv0,
                                                   const int* __restrict__ off,
                                                   unsigned short* __restrict__ hb, int N, int E) {
    int tid = threadIdx.x;
    int c = blockIdx.x & 7, h = c >> 1;
    int gblk = blockIdx.x >> 3, G = gridDim.x >> 3;
    int grp = tid >> 2, ld = tid & 3;    // 64 groups x 4 lanes; lane covers 8 dims
    const char* Fb = (const char*)(featS + (size_t)c * (size_t)N * 32) + ld * 16;
    const uint2* PH = pk0 + (size_t)h * E;
    for (int n = gblk * 64 + grp; n < N; n += G * 64) {
        int base = off[n], deg = off[n + 1] - base;
        float a0 = 0.f, a1 = 0.f, a2 = 0.f, a3 = 0.f;
        float a4 = 0.f, a5 = 0.f, a6 = 0.f, a7 = 0.f;
        const uint2* P = PH + base;
        for (int j = 0; j < deg; ++j) {
            uint2 p = P[j];
            float w = __uint_as_float(p.y);
            uint4 u = *(const uint4*)(Fb + p.x);
            a0 += w * blo(u.x); a1 += w * bhi(u.x);
            a2 += w * blo(u.y); a3 += w * bhi(u.y);
            a4 += w * blo(u.z); a5 += w * bhi(u.z);
            a6 += w * blo(u.w); a7 += w * bhi(u.w);
        }
        float inv = dinv0[n * 4 + h];
        float v0 = a0 * inv, v1 = a1 * inv, v2 = a2 * inv, v3 = a3 * inv;
        float v4 = a4 * inv, v5 = a5 * inv, v6 = a6 * inv, v7 = a7 * inv;
        v0 = v0 > 0.f ? v0 : (__expf(v0) - 1.f);
        v1 = v1 > 0.f ? v1 : (__expf(v1) - 1.f);
        v2 = v2 > 0.f ? v2 : (__expf(v2) - 1.f);
        v3 = v3 > 0.f ? v3 : (__expf(v3) - 1.f);
        v4 = v4 > 0.f ? v4 : (__expf(v4) - 1.f);
        v5 = v5 > 0.f ? v5 : (__expf(v5) - 1.f);
        v6 = v6 > 0.f ? v6 : (__expf(v6) - 1.f);
        v7 = v7 > 0.f ? v7 : (__expf(v7) - 1.f);
        uint4 o;
        o.x = bf16u(v0) | (bf16u(v1) << 16);
        o.y = bf16u(v2) | (bf16u(v3) << 16);
        o.z = bf16u(v4) | (bf16u(v5) << 16);
        o.w = bf16u(v6) | (bf16u(v7) << 16);
        *(uint4*)&hb[(size_t)n * 256 + c * 32 + ld * 8] = o;
    }
}

// ---- layer1 aggregation + residual: 8-lane group per node ------------------------
__global__ __launch_bounds__(256) void agg1_kernel(const float* __restrict__ fcat,
                                                   const uint2* __restrict__ pk1,
                                                   const float* __restrict__ dinv1,
                                                   const int* __restrict__ off,
                                                   float* __restrict__ out, int N) {
    int tid = threadIdx.x;
    int grp = tid >> 3, ld = tid & 7;    // 32 groups x 8 lanes; lane covers 4 dims
    const char* Fb = (const char*)fcat + ld * 16;
    for (int n = blockIdx.x * 32 + grp; n < N; n += gridDim.x * 32) {
        int base = off[n], deg = off[n + 1] - base;
        float a0 = 0.f, a1 = 0.f, a2 = 0.f, a3 = 0.f;
        const uint2* P = pk1 + base;
        for (int j = 0; j < deg; ++j) {
            uint2 p = P[j];
            float w = __uint_as_float(p.y);
            float4 f = *(const float4*)(Fb + p.x);
            a0 += w * f.x; a1 += w * f.y; a2 += w * f.z; a3 += w * f.w;
        }
        float inv = dinv1[n];
        float4 res = *(const float4*)&fcat[(size_t)n * 64 + 32 + ld * 4];
        float4 o;
        o.x = a0 * inv + res.x;
        o.y = a1 * inv + res.y;
        o.z = a2 * inv + res.z;
        o.w = a3 * inv + res.w;
        *(float4*)&out[(size_t)n * 32 + ld * 4] = o;
    }
}

extern "C" void kernel_launch(void* const* d_in, const int* in_sizes, int n_in,
                              void* d_out, int out_size, void* d_ws, size_t ws_size,
                              hipStream_t stream) {
    const float* x    = (const float*)d_in[0];
    const int*   src  = (const int*)d_in[1];
    const int*   dst  = (const int*)d_in[2];
    const float* W0   = (const float*)d_in[3];
    const float* al0  = (const float*)d_in[4];
    const float* ar0  = (const float*)d_in[5];
    const float* W1   = (const float*)d_in[6];
    const float* al1  = (const float*)d_in[7];
    const float* ar1  = (const float*)d_in[8];
    const float* Wres = (const float*)d_in[9];
    float* out = (float*)d_out;

    const int N = in_sizes[0] / 256;  // 50000
    const int E = in_sizes[1];        // 850000

    // workspace layout
    unsigned short* hb    = (unsigned short*)d_ws;                // N*256 bf16
    unsigned short* featS = hb + (size_t)N * 256;                 // [8][N][32] bf16
    unsigned short* W0P   = featS + (size_t)N * 256;              // [8][256][32] bf16
    unsigned short* Bt1   = W0P + 256 * 256;                      // 64*256 bf16
    float* fcat  = (float*)(Bt1 + 64 * 256);                      // N*64 fp32
    float* el0   = fcat + (size_t)N * 64;                         // N*4
    float* er0   = el0 + (size_t)N * 4;                           // N*4
    float* el1   = er0 + (size_t)N * 4;                           // N
    float* er1   = el1 + N;                                       // N
    float* dinv0 = er1 + N;                                       // N*4
    float* dinv1 = dinv0 + (size_t)N * 4;                         // N
    uint2* pk0   = (uint2*)(dinv1 + N);                           // E*4
    uint2* pk1   = pk0 + (size_t)E * 4;                           // E
    int*   deg    = (int*)(pk1 + E);                              // N
    int*   cursor = deg + N;                                      // N
    unsigned* gmax = (unsigned*)(cursor + N);                     // 16
    int*   offs  = (int*)(gmax + 16);                             // N+1
    int*   bsum  = offs + N + 1;                                  // 256
    int*   bpre  = bsum + 256;                                    // 256
    int*   csr_src = bpre + 256;                                  // E

    const int nb = (N + 255) / 256;
    const int eb = (E + 255) / 256;
    const int mb = (N + 63) / 64;

    // zero: deg, cursor, gmax (contiguous)
    hipMemsetAsync(deg, 0, (size_t)(2 * N + 16) * sizeof(int), stream);

    // prep (W0 panels + Bt1) fused with degree count
    prep_kernel<<<320 + eb, 256, 0, stream>>>(W0, W0P, W1, Wres, Bt1, dst, deg, E);

    // CSR
    scanA<<<nb, 256, 0, stream>>>(deg, bsum, N);
    scanB<<<1, 256, 0, stream>>>(bsum, bpre, nb);
    scanC<<<nb, 256, 0, stream>>>(deg, bpre, offs, N);
    scatter_kernel<<<eb, 256, 0, stream>>>(src, dst, offs, cursor, csr_src, E);

    // layer 0
    gemm0_all<<<mb, 256, 0, stream>>>(x, W0P, featS, el0, er0, al0, ar0, gmax, N);
    w0norm<<<512, 256, 0, stream>>>(el0, er0, gmax, offs, csr_src, pk0, dinv0, N, E);
    {
        int G = (N + 63) / 64;
        agg0_kernel<<<G * 8, 256, 0, stream>>>(featS, pk0, dinv0, offs, hb, N, E);
    }

    // layer 1
    gemm1_fused<<<mb, 256, 0, stream>>>(hb, Bt1, fcat, el1, er1, al1, ar1, gmax, N);
    w1norm<<<512, 256, 0, stream>>>(el1, er1, gmax, offs, csr_src, pk1, dinv1, N);
    {
        int G = (N + 31) / 32;
        agg1_kernel<<<G, 256, 0, stream>>>(fcat, pk1, dinv1, offs, out, N);
    }
}